// Round 1
// baseline (488.637 us; speedup 1.0000x reference)
//
#include <hip/hip_runtime.h>
#include <math.h>

#define HH 256
#define WW 256
#define CC 21
#define BB 16
#define HW (HH*WW)
#define CHW (CC*HW)
#define PHASE_OFF (BB*CHW)
#define AMP_OFF (PHASE_OFF + BB*HW)

static constexpr float DT = 0.1f;

__device__ __forceinline__ int xidx(int b, int c, int y, int x) {
    return ((b*CC + c)*HH + y)*WW + x;
}

// ---------------- Kernel 1: reaction (new_a, new_b, new_d -> ws) ----------------
__global__ __launch_bounds__(256)
void k1_react(const float* __restrict__ x,
              const float* __restrict__ slow_w, const float* __restrict__ slow_b,
              const float* __restrict__ alpha_p, const float* __restrict__ beta_p,
              const float* __restrict__ omega_p, const float* __restrict__ K_p,
              const float* __restrict__ kappa_p,
              float* __restrict__ wa, float* __restrict__ wb, float* __restrict__ wd)
{
    const int gx = blockIdx.x*32 + threadIdx.x;
    const int gy = blockIdx.y*8 + threadIdx.y;
    const int bb = blockIdx.z;
    const float alpha = alpha_p[0], beta = beta_p[0], omega = omega_p[0];
    const float Kc = K_p[0], kappa = kappa_p[0];

    // LAP/12 conv (zero-pad), min_pool3 (inf-pad) on ch3; LAP/12 on ch15,16,17
    float lap3 = 0.f, lapA = 0.f, lapB = 0.f, lapD = 0.f;
    float emin = INFINITY;
    float c3 = 0.f, a = 0.f, b = 0.f, d = 0.f;
    #pragma unroll
    for (int dy = -1; dy <= 1; dy++) {
        #pragma unroll
        for (int dx = -1; dx <= 1; dx++) {
            const int yy = gy + dy, xx = gx + dx;
            const bool inb = (yy >= 0) && (yy < HH) && (xx >= 0) && (xx < WW);
            if (inb) {
                const float v3 = x[xidx(bb, 3, yy, xx)];
                const float va = x[xidx(bb, 15, yy, xx)];
                const float vb = x[xidx(bb, 16, yy, xx)];
                const float vd = x[xidx(bb, 17, yy, xx)];
                const float lw = ((dy == 0 && dx == 0) ? -12.f
                                 : ((dy == 0 || dx == 0) ? 2.f : 1.f)) * (1.f/12.f);
                lap3 = fmaf(lw, v3, lap3);
                lapA = fmaf(lw, va, lapA);
                lapB = fmaf(lw, vb, lapB);
                lapD = fmaf(lw, vd, lapD);
                emin = fminf(emin, v3);
                if (dy == 0 && dx == 0) { c3 = v3; a = va; b = vb; d = vd; }
            }
        }
    }
    const float c4 = x[xidx(bb, 4, gy, gx)];
    const float c5 = x[xidx(bb, 5, gy, gx)];
    const float Q0 = c3, Q1 = c3 - emin, Q2 = lap3, Q3 = c4, Q4 = c5;
    float I[3];
    #pragma unroll
    for (int j = 0; j < 3; j++) {
        float acc = slow_b[j];
        acc = fmaf(slow_w[j*5+0], Q0, acc);
        acc = fmaf(slow_w[j*5+1], Q1, acc);
        acc = fmaf(slow_w[j*5+2], Q2, acc);
        acc = fmaf(slow_w[j*5+3], Q3, acc);
        acc = fmaf(slow_w[j*5+4], Q4, acc);
        I[j] = acc;
    }
    const float na = a + DT * (-alpha*a + omega*b + Kc*lapA + I[0]);
    const float nb = b + DT * (-alpha*b - omega*a + Kc*lapB + I[1]);
    const float nd = d + DT * (-beta*d + kappa*lapD + I[2]);
    const int o = (bb*HH + gy)*WW + gx;
    wa[o] = na; wb[o] = nb; wd[o] = nd;
}

// ---------------- Kernel 2: avg_pool5 + normalize + phase/amp + mod ----------------
__global__ __launch_bounds__(256)
void k2_pool(const float* __restrict__ wa, const float* __restrict__ wb,
             const float* __restrict__ wd,
             const float* __restrict__ mod_w, const float* __restrict__ mod_b,
             float* __restrict__ out)
{
    __shared__ float ta[12][36];
    __shared__ float tb[12][36];
    const int tx = threadIdx.x, ty = threadIdx.y;
    const int bb = blockIdx.z;
    const int X0 = blockIdx.x*32, Y0 = blockIdx.y*8;
    const int tid = ty*32 + tx;
    const float* basea = wa + bb*HW;
    const float* baseb = wb + bb*HW;
    for (int i = tid; i < 12*36; i += 256) {
        const int r = i / 36, cc = i % 36;
        const int yy = Y0 + r - 2, xx = X0 + cc - 2;
        const bool inb = (yy >= 0) && (yy < HH) && (xx >= 0) && (xx < WW);
        ta[r][cc] = inb ? basea[yy*WW + xx] : 0.f;
        tb[r][cc] = inb ? baseb[yy*WW + xx] : 0.f;
    }
    __syncthreads();
    const int lx = tx + 2, ly = ty + 2;
    float sa = 0.f, sb = 0.f;
    #pragma unroll
    for (int dy = -2; dy <= 2; dy++) {
        #pragma unroll
        for (int dx = -2; dx <= 2; dx++) {
            sa += ta[ly+dy][lx+dx];
            sb += tb[ly+dy][lx+dx];
        }
    }
    sa *= (1.f/25.f); sb *= (1.f/25.f);
    const float rho = sqrtf(sa*sa + sb*sb + 1e-6f);
    const float an = sa / rho, bn = sb / rho;
    const float a0 = ta[ly][lx], b0 = tb[ly][lx];
    const float A2 = a0 + DT * (an - a0);
    const float B2 = b0 + DT * (bn - b0);
    const int gy = Y0 + ty, gx = X0 + tx;
    const float nd = wd[bb*HW + gy*WW + gx];
    const float ph = sqrtf(A2*A2 + B2*B2 + 1e-6f);
    const float am = atan2f(B2, A2);
    out[xidx(bb, 15, gy, gx)] = A2;
    out[xidx(bb, 16, gy, gx)] = B2;
    out[xidx(bb, 17, gy, gx)] = nd;
    #pragma unroll
    for (int j = 0; j < 3; j++) {
        out[xidx(bb, 18+j, gy, gx)] =
            mod_b[j] + mod_w[j*3+0]*A2 + mod_w[j*3+1]*B2 + mod_w[j*3+2]*nd;
    }
    out[PHASE_OFF + bb*HW + gy*WW + gx] = ph;
    out[AMP_OFF  + bb*HW + gy*WW + gx] = am;
}

// ---------------- Kernel 3: perception + MLP + gene update + prefix copy ----------------
__global__ __launch_bounds__(256)
void k3_gene(const float* __restrict__ x, const float* __restrict__ noise,
             const float* __restrict__ w1w, const float* __restrict__ w1b,
             const float* __restrict__ w2w,
             float* __restrict__ out)
{
    __shared__ float xt[CC][10][34];   // 21 ch, 8+2 rows, 32+2 cols (wrap halo)
    const int tx = threadIdx.x, ty = threadIdx.y;
    const int bb = blockIdx.z;
    const int X0 = blockIdx.x*32, Y0 = blockIdx.y*8;
    const int tid = ty*32 + tx;
    const float* xb = x + bb*CHW;
    for (int i = tid; i < CC*340; i += 256) {
        const int c = i / 340;
        const int rem = i - c*340;
        const int r = rem / 34;
        const int cc = rem - r*34;
        const int yy = (Y0 + r - 1) & (HH - 1);   // wrap
        const int xx = (X0 + cc - 1) & (WW - 1);  // wrap
        (&xt[0][0][0])[i] = xb[c*HW + yy*WW + xx];
    }
    __syncthreads();

    const int lx = tx + 1, ly = ty + 1;
    float p[84];
    #pragma unroll
    for (int c = 0; c < CC; c++) {
        const float n00 = xt[c][ly-1][lx-1], n01 = xt[c][ly-1][lx], n02 = xt[c][ly-1][lx+1];
        const float n10 = xt[c][ly  ][lx-1], n11 = xt[c][ly  ][lx], n12 = xt[c][ly  ][lx+1];
        const float n20 = xt[c][ly+1][lx-1], n21 = xt[c][ly+1][lx], n22 = xt[c][ly+1][lx+1];
        p[c] = n11;
        p[21 + 3*c + 0] = (n02 - n00) + 2.f*(n12 - n10) + (n22 - n20);          // sobel_x
        p[21 + 3*c + 1] = (n20 - n00) + 2.f*(n21 - n01) + (n22 - n02);          // sobel_y
        p[21 + 3*c + 2] = (n00 + n02 + n20 + n22) + 2.f*(n01 + n10 + n12 + n21) - 12.f*n11; // lap
    }

    float y0 = 0.f, y1 = 0.f, y2 = 0.f;
    #pragma unroll 2
    for (int h = 0; h < 96; h++) {
        float acc = w1b[h];
        const float* wrow = w1w + h*84;
        #pragma unroll
        for (int k = 0; k < 84; k++) acc = fmaf(wrow[k], p[k], acc);
        const float r = fmaxf(acc, 0.f);
        y0 = fmaf(w2w[h],       r, y0);
        y1 = fmaf(w2w[96 + h],  r, y1);
        y2 = fmaf(w2w[192 + h], r, y2);
    }

    // life: wrap max_pool3 of ch3 > 0.1  (halo in LDS already wrapped)
    float m = xt[3][ly-1][lx-1];
    m = fmaxf(m, xt[3][ly-1][lx]); m = fmaxf(m, xt[3][ly-1][lx+1]);
    m = fmaxf(m, xt[3][ly  ][lx-1]); m = fmaxf(m, xt[3][ly][lx]); m = fmaxf(m, xt[3][ly][lx+1]);
    m = fmaxf(m, xt[3][ly+1][lx-1]); m = fmaxf(m, xt[3][ly+1][lx]); m = fmaxf(m, xt[3][ly+1][lx+1]);
    const float life = (m > 0.1f) ? 1.f : 0.f;

    const int gy = Y0 + ty, gx = X0 + tx;
    const float mask = floorf(noise[bb*HW + gy*WW + gx] + 0.5f);
    const float g = mask * life;

    float* ob = out + bb*CHW;
    const int po = gy*WW + gx;
    #pragma unroll
    for (int c = 0; c < 12; c++) ob[c*HW + po] = xt[c][ly][lx];
    ob[12*HW + po] = xt[12][ly][lx] + y0 * g;
    ob[13*HW + po] = xt[13][ly][lx] + y1 * g;
    ob[14*HW + po] = xt[14][ly][lx] + y2 * g;
}

extern "C" void kernel_launch(void* const* d_in, const int* in_sizes, int n_in,
                              void* d_out, int out_size, void* d_ws, size_t ws_size,
                              hipStream_t stream)
{
    const float* x      = (const float*)d_in[0];
    const float* noise  = (const float*)d_in[1];
    const float* w1w    = (const float*)d_in[2];
    const float* w1b    = (const float*)d_in[3];
    const float* w2w    = (const float*)d_in[4];
    const float* sloww  = (const float*)d_in[5];
    const float* slowb  = (const float*)d_in[6];
    const float* modw   = (const float*)d_in[7];
    const float* modb   = (const float*)d_in[8];
    const float* alphap = (const float*)d_in[9];
    const float* betap  = (const float*)d_in[10];
    const float* omegap = (const float*)d_in[11];
    const float* Kp     = (const float*)d_in[12];
    const float* kappap = (const float*)d_in[13];
    float* out = (float*)d_out;

    float* wa = (float*)d_ws;
    float* wb = wa + (size_t)BB*HW;
    float* wd = wb + (size_t)BB*HW;

    dim3 blk(32, 8, 1);
    dim3 grd(WW/32, HH/8, BB);

    k1_react<<<grd, blk, 0, stream>>>(x, sloww, slowb, alphap, betap, omegap, Kp, kappap,
                                      wa, wb, wd);
    k2_pool<<<grd, blk, 0, stream>>>(wa, wb, wd, modw, modb, out);
    k3_gene<<<grd, blk, 0, stream>>>(x, noise, w1w, w1b, w2w, out);
}

// Round 2
// 314.700 us; speedup vs baseline: 1.5527x; 1.5527x over previous
//
#include <hip/hip_runtime.h>
#include <math.h>

#define HH 256
#define WW 256
#define CC 21
#define BB 16
#define HW (HH*WW)
#define CHW (CC*HW)
#define PHASE_OFF (BB*CHW)
#define AMP_OFF (PHASE_OFF + BB*HW)

static constexpr float DT = 0.1f;

typedef short short8 __attribute__((ext_vector_type(8)));
typedef float floatx4 __attribute__((ext_vector_type(4)));

__device__ __forceinline__ unsigned f2bf_bits(float f) {
    unsigned u = __builtin_bit_cast(unsigned, f);
    return (u + 0x7fffu + ((u >> 16) & 1u)) >> 16;   // RNE
}
__device__ __forceinline__ float bf2f(short s) {
    unsigned u = ((unsigned)(unsigned short)s) << 16;
    return __builtin_bit_cast(float, u);
}

// ---------- k0: convert+permute W1 (96x84 fp32) -> W1p (96x96 bf16, padded) ----------
// Feature order in P: k = 4*c + {0:id, 1:sobelx, 2:sobely, 3:lap}, c in 0..20; k>=84 zero.
__global__ __launch_bounds__(256)
void k0_prep(const float* __restrict__ w1w, short* __restrict__ w1p) {
    const int i = blockIdx.x * 256 + threadIdx.x;
    if (i >= 96 * 96) return;
    const int h = i / 96, kk = i - h * 96;
    const int c = kk >> 2, f = kk & 3;
    float v = 0.f;
    if (c < 21) {
        const int orig = (f == 0) ? c : (21 + 3 * c + (f - 1));
        v = w1w[h * 84 + orig];
    }
    w1p[i] = (short)f2bf_bits(v);
}

// ---------- k12: fused reaction + avg_pool5 + normalize + phase/amp + mod ----------
__global__ __launch_bounds__(256)
void k12_react(const float* __restrict__ x,
               const float* __restrict__ slow_w, const float* __restrict__ slow_b,
               const float* __restrict__ mod_w, const float* __restrict__ mod_b,
               const float* __restrict__ alpha_p, const float* __restrict__ beta_p,
               const float* __restrict__ omega_p, const float* __restrict__ K_p,
               const float* __restrict__ kappa_p,
               float* __restrict__ out)
{
    __shared__ float t[6][14][38];          // ch {3,4,5,15,16,17}, origin (Y0-3, X0-3)
    __shared__ float na[12][36], nb[12][36]; // new_a/new_b, origin (Y0-2, X0-2)

    const int tx = threadIdx.x, ty = threadIdx.y;
    const int bb = blockIdx.z;
    const int X0 = blockIdx.x * 32, Y0 = blockIdx.y * 8;
    const int tid = ty * 32 + tx;

    const float alpha = alpha_p[0], beta = beta_p[0], omega = omega_p[0];
    const float Kc = K_p[0], kappa = kappa_p[0];

    // stage 6 channels, 14x38, zero-filled OOB
    const int chs[6] = {3, 4, 5, 15, 16, 17};
    for (int i = tid; i < 6 * 532; i += 256) {
        const int ch = i / 532;
        const int rem = i - ch * 532;
        const int r = rem / 38, c = rem - r * 38;
        const int gy = Y0 + r - 3, gx = X0 + c - 3;
        const bool inb = (gy >= 0) && (gy < HH) && (gx >= 0) && (gx < WW);
        t[ch][r][c] = inb ? x[((bb * CC + chs[ch]) * HH + gy) * WW + gx] : 0.f;
    }
    __syncthreads();

    // compute new_a / new_b on 36x12 (zero where OOB)
    for (int i = tid; i < 432; i += 256) {
        const int r2 = i / 36, c2 = i - r2 * 36;
        const int gy = Y0 + r2 - 2, gx = X0 + c2 - 2;
        float va = 0.f, vb = 0.f;
        if (gy >= 0 && gy < HH && gx >= 0 && gx < WW) {
            const int lr = r2 + 1, lc = c2 + 1;
            float lap3 = 0.f, lapA = 0.f, lapB = 0.f, emin = INFINITY;
            #pragma unroll
            for (int dy = -1; dy <= 1; dy++) {
                #pragma unroll
                for (int dx = -1; dx <= 1; dx++) {
                    const float lw = ((dy == 0 && dx == 0) ? -12.f
                                     : ((dy == 0 || dx == 0) ? 2.f : 1.f)) * (1.f / 12.f);
                    const float v3 = t[0][lr + dy][lc + dx];
                    lap3 = fmaf(lw, v3, lap3);
                    lapA = fmaf(lw, t[3][lr + dy][lc + dx], lapA);
                    lapB = fmaf(lw, t[4][lr + dy][lc + dx], lapB);
                    const bool nin = (gy + dy >= 0) && (gy + dy < HH) && (gx + dx >= 0) && (gx + dx < WW);
                    emin = fminf(emin, nin ? v3 : INFINITY);
                }
            }
            const float Q0 = t[0][lr][lc];
            const float Q1 = Q0 - emin, Q2 = lap3;
            const float Q3 = t[1][lr][lc], Q4 = t[2][lr][lc];
            const float I0 = slow_b[0] + slow_w[0] * Q0 + slow_w[1] * Q1 + slow_w[2] * Q2 + slow_w[3] * Q3 + slow_w[4] * Q4;
            const float I1 = slow_b[1] + slow_w[5] * Q0 + slow_w[6] * Q1 + slow_w[7] * Q2 + slow_w[8] * Q3 + slow_w[9] * Q4;
            const float a = t[3][lr][lc], b = t[4][lr][lc];
            va = a + DT * (-alpha * a + omega * b + Kc * lapA + I0);
            vb = b + DT * (-alpha * b - omega * a + Kc * lapB + I1);
        }
        na[r2][c2] = va;
        nb[r2][c2] = vb;
    }
    __syncthreads();

    // per-center: avg5, normalize, nd, outputs
    const int gy = Y0 + ty, gx = X0 + tx;
    const int lr = ty + 3, lc = tx + 3;

    float sa = 0.f, sb = 0.f;
    #pragma unroll
    for (int dy = 0; dy < 5; dy++)
        #pragma unroll
        for (int dx = 0; dx < 5; dx++) {
            sa += na[ty + dy][tx + dx];
            sb += nb[ty + dy][tx + dx];
        }
    sa *= (1.f / 25.f); sb *= (1.f / 25.f);
    const float rho = sqrtf(sa * sa + sb * sb + 1e-6f);
    const float an = sa / rho, bn = sb / rho;
    const float a0 = na[ty + 2][tx + 2], b0 = nb[ty + 2][tx + 2];
    const float A2 = a0 + DT * (an - a0);
    const float B2 = b0 + DT * (bn - b0);

    // nd at center
    float lapD = 0.f, lap3 = 0.f, emin = INFINITY;
    #pragma unroll
    for (int dy = -1; dy <= 1; dy++)
        #pragma unroll
        for (int dx = -1; dx <= 1; dx++) {
            const float lw = ((dy == 0 && dx == 0) ? -12.f
                             : ((dy == 0 || dx == 0) ? 2.f : 1.f)) * (1.f / 12.f);
            lapD = fmaf(lw, t[5][lr + dy][lc + dx], lapD);
            const float v3 = t[0][lr + dy][lc + dx];
            lap3 = fmaf(lw, v3, lap3);
            const bool nin = (gy + dy >= 0) && (gy + dy < HH) && (gx + dx >= 0) && (gx + dx < WW);
            emin = fminf(emin, nin ? v3 : INFINITY);
        }
    const float Q0 = t[0][lr][lc];
    const float I2 = slow_b[2] + slow_w[10] * Q0 + slow_w[11] * (Q0 - emin) + slow_w[12] * lap3
                   + slow_w[13] * t[1][lr][lc] + slow_w[14] * t[2][lr][lc];
    const float d0 = t[5][lr][lc];
    const float nd = d0 + DT * (-beta * d0 + kappa * lapD + I2);

    const float ph = sqrtf(A2 * A2 + B2 * B2 + 1e-6f);
    const float am = atan2f(B2, A2);

    const int po = gy * WW + gx;
    float* ob = out + bb * CHW;
    ob[15 * HW + po] = A2;
    ob[16 * HW + po] = B2;
    ob[17 * HW + po] = nd;
    #pragma unroll
    for (int j = 0; j < 3; j++)
        ob[(18 + j) * HW + po] = mod_b[j] + mod_w[j * 3 + 0] * A2 + mod_w[j * 3 + 1] * B2 + mod_w[j * 3 + 2] * nd;
    out[PHASE_OFF + bb * HW + po] = ph;
    out[AMP_OFF + bb * HW + po] = am;
}

// ---------- k3: perception -> MFMA GEMM (84->96) -> readback (96->3) -> gene ----------
__global__ __launch_bounds__(256, 2)
void k3_gene(const float* __restrict__ x, const float* __restrict__ noise,
             const short* __restrict__ w1p, const float* __restrict__ w1b,
             const float* __restrict__ w2w,
             float* __restrict__ out)
{
    __shared__ __align__(16) short P[256 * 96];   // P (bf16), then overwritten by H in-place
    __shared__ float xt[CC][10][34];              // wrap-padded x tile (fp32)

    const int tx = threadIdx.x & 31;
    const int ty = (threadIdx.y * blockDim.x + threadIdx.x) >> 5;  // block is (32,8)
    const int tid = threadIdx.y * 32 + threadIdx.x;
    const int bb = blockIdx.z;
    const int X0 = blockIdx.x * 32, Y0 = blockIdx.y * 8;
    const float* xb = x + bb * CHW;

    // ---- phase 1: stage x tile (wrap halo) ----
    for (int i = tid; i < CC * 340; i += 256) {
        const int c = i / 340;
        const int rem = i - c * 340;
        const int r = rem / 34;
        const int cc = rem - r * 34;
        const int yy = (Y0 + r - 1) & (HH - 1);
        const int xx = (X0 + cc - 1) & (WW - 1);
        (&xt[0][0][0])[i] = xb[c * HW + yy * WW + xx];
    }
    __syncthreads();

    // ---- phase 2: per-pixel features -> P (bf16), plus life/mask/prefix ----
    const int lx = tx + 1, ly = ty + 1;
    #pragma unroll
    for (int c = 0; c < CC; c++) {
        const float n00 = xt[c][ly - 1][lx - 1], n01 = xt[c][ly - 1][lx], n02 = xt[c][ly - 1][lx + 1];
        const float n10 = xt[c][ly][lx - 1],     n11 = xt[c][ly][lx],     n12 = xt[c][ly][lx + 1];
        const float n20 = xt[c][ly + 1][lx - 1], n21 = xt[c][ly + 1][lx], n22 = xt[c][ly + 1][lx + 1];
        const float fid = n11;
        const float fsx = (n02 - n00) + 2.f * (n12 - n10) + (n22 - n20);
        const float fsy = (n20 - n00) + 2.f * (n21 - n01) + (n22 - n02);
        const float flap = (n00 + n02 + n20 + n22) + 2.f * (n01 + n10 + n12 + n21) - 12.f * n11;
        const unsigned lo = f2bf_bits(fid) | (f2bf_bits(fsx) << 16);
        const unsigned hi = f2bf_bits(fsy) | (f2bf_bits(flap) << 16);
        unsigned* dst = (unsigned*)(P + tid * 96 + 4 * c);
        *(uint2*)dst = make_uint2(lo, hi);
    }
    {   // zero pad features 84..95
        unsigned* dst = (unsigned*)(P + tid * 96 + 84);
        *(uint2*)(dst)     = make_uint2(0u, 0u);
        *(uint2*)(dst + 2) = make_uint2(0u, 0u);
        *(uint2*)(dst + 4) = make_uint2(0u, 0u);
    }

    float m = xt[3][ly - 1][lx - 1];
    m = fmaxf(m, xt[3][ly - 1][lx]); m = fmaxf(m, xt[3][ly - 1][lx + 1]);
    m = fmaxf(m, xt[3][ly][lx - 1]); m = fmaxf(m, xt[3][ly][lx]); m = fmaxf(m, xt[3][ly][lx + 1]);
    m = fmaxf(m, xt[3][ly + 1][lx - 1]); m = fmaxf(m, xt[3][ly + 1][lx]); m = fmaxf(m, xt[3][ly + 1][lx + 1]);
    const float life = (m > 0.1f) ? 1.f : 0.f;
    const int gy = Y0 + ty, gx = X0 + tx;
    const int po = gy * WW + gx;
    const float g = floorf(noise[bb * HW + po] + 0.5f) * life;
    const float c12 = xt[12][ly][lx], c13 = xt[13][ly][lx], c14 = xt[14][ly][lx];

    float* ob = out + bb * CHW;
    #pragma unroll
    for (int c = 0; c < 12; c++) ob[c * HW + po] = xt[c][ly][lx];
    __syncthreads();

    // ---- phase 3: GEMM H = relu(P * W1^T + b), H overwrites P in place ----
    {
        const int w = tid >> 6;
        const int lane = tid & 63;
        const int ln = lane & 15;       // n (hidden) within tile / m row for A
        const int kg = lane >> 4;       // k-group 0..3

        float bias[6];
        #pragma unroll
        for (int nt = 0; nt < 6; nt++) bias[nt] = w1b[nt * 16 + ln];

        short8 bfr[18];
        #pragma unroll
        for (int nt = 0; nt < 6; nt++)
            #pragma unroll
            for (int ks = 0; ks < 3; ks++)
                bfr[nt * 3 + ks] = *(const short8*)(w1p + (nt * 16 + ln) * 96 + ks * 32 + kg * 8);

        #pragma unroll
        for (int mt = 0; mt < 4; mt++) {
            const int m0 = w * 64 + mt * 16;
            const short* arow = P + (m0 + ln) * 96 + kg * 8;
            const short8 a0 = *(const short8*)(arow);
            const short8 a1 = *(const short8*)(arow + 32);
            const short8 a2 = *(const short8*)(arow + 64);

            floatx4 acc[6];
            #pragma unroll
            for (int nt = 0; nt < 6; nt++) {
                floatx4 c4 = {0.f, 0.f, 0.f, 0.f};
                c4 = __builtin_amdgcn_mfma_f32_16x16x32_bf16(a0, bfr[nt * 3 + 0], c4, 0, 0, 0);
                c4 = __builtin_amdgcn_mfma_f32_16x16x32_bf16(a1, bfr[nt * 3 + 1], c4, 0, 0, 0);
                c4 = __builtin_amdgcn_mfma_f32_16x16x32_bf16(a2, bfr[nt * 3 + 2], c4, 0, 0, 0);
                acc[nt] = c4;
            }
            // write H rows for this m-tile (rows are wave-private)
            #pragma unroll
            for (int nt = 0; nt < 6; nt++)
                #pragma unroll
                for (int r = 0; r < 4; r++) {
                    float h = acc[nt][r] + bias[nt];
                    h = fmaxf(h, 0.f);
                    P[(m0 + kg * 4 + r) * 96 + nt * 16 + ln] = (short)f2bf_bits(h);
                }
        }
    }
    __syncthreads();

    // ---- phase 4: y = H * W2^T, gene update ----
    float y0 = 0.f, y1 = 0.f, y2 = 0.f;
    const short* hrow = P + tid * 96;
    #pragma unroll
    for (int gq = 0; gq < 12; gq++) {
        const short8 hv = *(const short8*)(hrow + gq * 8);
        #pragma unroll
        for (int j = 0; j < 8; j++) {
            const float h = bf2f(hv[j]);
            y0 = fmaf(w2w[gq * 8 + j], h, y0);
            y1 = fmaf(w2w[96 + gq * 8 + j], h, y1);
            y2 = fmaf(w2w[192 + gq * 8 + j], h, y2);
        }
    }
    ob[12 * HW + po] = c12 + y0 * g;
    ob[13 * HW + po] = c13 + y1 * g;
    ob[14 * HW + po] = c14 + y2 * g;
}

extern "C" void kernel_launch(void* const* d_in, const int* in_sizes, int n_in,
                              void* d_out, int out_size, void* d_ws, size_t ws_size,
                              hipStream_t stream)
{
    const float* x      = (const float*)d_in[0];
    const float* noise  = (const float*)d_in[1];
    const float* w1w    = (const float*)d_in[2];
    const float* w1b    = (const float*)d_in[3];
    const float* w2w    = (const float*)d_in[4];
    const float* sloww  = (const float*)d_in[5];
    const float* slowb  = (const float*)d_in[6];
    const float* modw   = (const float*)d_in[7];
    const float* modb   = (const float*)d_in[8];
    const float* alphap = (const float*)d_in[9];
    const float* betap  = (const float*)d_in[10];
    const float* omegap = (const float*)d_in[11];
    const float* Kp     = (const float*)d_in[12];
    const float* kappap = (const float*)d_in[13];
    float* out = (float*)d_out;

    short* w1p = (short*)d_ws;   // 96*96 bf16 = 18432 B

    dim3 blk(32, 8, 1);
    dim3 grd(WW / 32, HH / 8, BB);

    k0_prep<<<dim3(36), dim3(256), 0, stream>>>(w1w, w1p);
    k12_react<<<grd, blk, 0, stream>>>(x, sloww, slowb, modw, modb,
                                       alphap, betap, omegap, Kp, kappap, out);
    k3_gene<<<grd, blk, 0, stream>>>(x, noise, w1p, w1b, w2w, out);
}